// Round 8
// baseline (3053.142 us; speedup 1.0000x reference)
//
#include <hip/hip_runtime.h>
#include <hip/hip_bf16.h>

// Problem constants (match reference)
#define NN 100000
#define NG 512
#define H  128

// dst-block aggregation geometry
#define BN    120                 // dst nodes per workgroup
#define BPAD  132                 // padded accumulator row (floats)
#define NBLK  834                 // ceil(100000/120)
#define SB    98                  // src buckets (src>>10), 100000>>10=97 -> 98
#define NCELL_PAD 81920           // NBLK*SB=81732 padded to 320*256

typedef _Float16 half8 __attribute__((ext_vector_type(8)));
typedef float f32x4 __attribute__((ext_vector_type(4)));

// ---------------------------------------------------------------------------
// count edges per (dst-block, src-bucket) cell + dst in-degree
__global__ __launch_bounds__(256) void k_count(const int* __restrict__ src,
                                               const int* __restrict__ dst,
                                               int* __restrict__ cellCnt,
                                               int* __restrict__ deg, int E) {
    int e = blockIdx.x * 256 + threadIdx.x;
    if (e >= E) return;
    int d = dst[e], s = src[e];
    atomicAdd(&cellCnt[(d / BN) * SB + (s >> 10)], 1);
    atomicAdd(&deg[d], 1);
}

// per-block exclusive scan (256 elems), partial sums to bsum
__global__ __launch_bounds__(256) void k_scan_block(const int* __restrict__ in,
                                                    int* __restrict__ outp,
                                                    int* __restrict__ bsum, int n) {
    __shared__ int s[256];
    int tid = threadIdx.x;
    int i = blockIdx.x * 256 + tid;
    int v = (i < n) ? in[i] : 0;
    s[tid] = v;
    __syncthreads();
    #pragma unroll
    for (int off = 1; off < 256; off <<= 1) {
        int t = (tid >= off) ? s[tid - off] : 0;
        __syncthreads();
        s[tid] += t;
        __syncthreads();
    }
    if (i < n) outp[i] = s[tid] - v;              // exclusive within block
    if (tid == 255) bsum[blockIdx.x] = s[255];    // block total
}

// scan of block sums (nb <= 512), single block
__global__ __launch_bounds__(512) void k_scan_top(int* __restrict__ bsum, int nb) {
    __shared__ int s[512];
    int tid = threadIdx.x;
    int v = (tid < nb) ? bsum[tid] : 0;
    s[tid] = v;
    __syncthreads();
    #pragma unroll
    for (int off = 1; off < 512; off <<= 1) {
        int t = (tid >= off) ? s[tid - off] : 0;
        __syncthreads();
        s[tid] += t;
        __syncthreads();
    }
    if (tid < nb) bsum[tid] = s[tid] - v;         // exclusive
}

// add block offsets; copy to cursor
__global__ __launch_bounds__(256) void k_scan_fin2(int* __restrict__ off,
                                                   const int* __restrict__ bsum,
                                                   int* __restrict__ cursor, int n) {
    int i = blockIdx.x * 256 + threadIdx.x;
    if (i >= n) return;
    int r = off[i] + bsum[i >> 8];
    off[i] = r;
    cursor[i] = r;
}

__global__ __launch_bounds__(256) void k_dinv(const int* __restrict__ deg,
                                              float* __restrict__ dinv, int n) {
    int i = blockIdx.x * 256 + threadIdx.x;
    if (i < n) dinv[i] = rsqrtf((float)deg[i] + 1.0f);
}

// scatter edges into cell-grouped array: packed = src<<8 | dstLocal
__global__ __launch_bounds__(256) void k_fill2(const int* __restrict__ src,
                                               const int* __restrict__ dst,
                                               int* __restrict__ cursor,
                                               unsigned* __restrict__ earr, int E) {
    int e = blockIdx.x * 256 + threadIdx.x;
    if (e >= E) return;
    int d = dst[e], s = src[e];
    int g = d / BN;
    int pos = atomicAdd(&cursor[g * SB + (s >> 10)], 1);
    earr[pos] = ((unsigned)s << 8) | (unsigned)(d - g * BN);
}

// ---------------------------------------------------------------------------
// fp32 -> fp16 conversion (for x)
__global__ __launch_bounds__(256) void k_cvt_h(const float* __restrict__ in,
                                               _Float16* __restrict__ out, int n4) {
    int i = blockIdx.x * 256 + threadIdx.x;
    if (i >= n4) return;
    float4 v = ((const float4*)in)[i];
    _Float16 h0 = (_Float16)v.x, h1 = (_Float16)v.y;
    _Float16 h2 = (_Float16)v.z, h3 = (_Float16)v.w;
    _Float16* o = out + 4 * (size_t)i;
    o[0] = h0; o[1] = h1; o[2] = h2; o[3] = h3;
}

// ---------------------------------------------------------------------------
// MFMA GEMM: C_h[n x 128] (fp16) = (A_h @ W) * scale[row]; 64 rows/block.
#define LDA 136   // 128 + 8 fp16 pad
__global__ __launch_bounds__(256) void gemm_mfma(const _Float16* __restrict__ A,
                                                 const float* __restrict__ W,
                                                 const float* __restrict__ scale,
                                                 _Float16* __restrict__ C, int n) {
    __shared__ _Float16 As[64 * LDA];
    __shared__ _Float16 Wt[128 * LDA];
    const int tid = threadIdx.x;
    const int row0 = blockIdx.x * 64;

    #pragma unroll
    for (int i = 0; i < 4; ++i) {
        int f = i * 256 + tid;
        int r = f >> 4, c8 = f & 15;
        int gr = row0 + r;
        half8 v;
        #pragma unroll
        for (int j = 0; j < 8; ++j) v[j] = (_Float16)0.0f;
        if (gr < n) v = ((const half8*)(A + (size_t)gr * H))[c8];
        *((half8*)(As + r * LDA + c8 * 8)) = v;
    }
    #pragma unroll
    for (int i = 0; i < 16; ++i) {
        int f = i * 256 + tid;
        int k = f >> 5, c4 = f & 31;
        float4 v = ((const float4*)(W + (size_t)k * H))[c4];
        Wt[(c4 * 4 + 0) * LDA + k] = (_Float16)v.x;
        Wt[(c4 * 4 + 1) * LDA + k] = (_Float16)v.y;
        Wt[(c4 * 4 + 2) * LDA + k] = (_Float16)v.z;
        Wt[(c4 * 4 + 3) * LDA + k] = (_Float16)v.w;
    }
    __syncthreads();

    const int w = tid >> 6;
    const int lane = tid & 63;
    const int l16 = lane & 15, quad = lane >> 4;
    f32x4 acc[8] = {};
    const _Float16* aBase = As + (w * 16 + l16) * LDA + quad * 8;
    const _Float16* bBase = Wt + l16 * LDA + quad * 8;
    #pragma unroll
    for (int kk = 0; kk < 4; ++kk) {
        half8 af = *((const half8*)(aBase + kk * 32));
        #pragma unroll
        for (int nt = 0; nt < 8; ++nt) {
            half8 bf = *((const half8*)(bBase + nt * 16 * LDA + kk * 32));
            acc[nt] = __builtin_amdgcn_mfma_f32_16x16x32_f16(af, bf, acc[nt], 0, 0, 0);
        }
    }
    #pragma unroll
    for (int r = 0; r < 4; ++r) {
        int R = row0 + w * 16 + quad * 4 + r;
        if (R < n) {
            float sc = scale[R];
            _Float16* crow = C + (size_t)R * H + l16;
            #pragma unroll
            for (int nt = 0; nt < 8; ++nt)
                crow[nt * 16] = (_Float16)(acc[nt][r] * sc);
        }
    }
}

// ---------------------------------------------------------------------------
// edge aggregation core: quarter-wave q handles edge slot 4g+q; lane loads
// 16B (8 halves) of the src row and atomically adds into the LDS accumulator
// row of the edge's dstLocal. Rotated feature order -> ~2-way LDS aliasing.
__device__ __forceinline__ void agg_add(float* __restrict__ row, int l16, half8 v) {
    #pragma unroll
    for (int i = 0; i < 8; ++i) {
        int ii = (l16 + i) & 7;
        atomicAdd(row + l16 * 8 + ii, (float)v[ii]);
    }
}

__device__ __forceinline__ void agg_edges(float* __restrict__ acc,
                                          const half8* __restrict__ t8,
                                          const unsigned* __restrict__ earr,
                                          int gs, int ge) {
    const int tid = threadIdx.x;
    const int w = tid >> 6;
    const int lane = tid & 63;
    const int q = lane >> 4, l16 = lane & 15;
    for (int base = gs + w * 64; base < ge; base += 256) {
        int ce = base + lane;
        unsigned cidx = (ce < ge) ? earr[ce] : 0u;
        int m = min(64, ge - base);
        int nf = m >> 2;
        int g = 0;
        for (; g + 2 <= nf; g += 2) {
            unsigned p0 = (unsigned)__shfl((int)cidx, 4 * g + q);
            unsigned p1 = (unsigned)__shfl((int)cidx, 4 * g + 4 + q);
            int s0 = p0 >> 8, dl0 = p0 & 255;
            int s1 = p1 >> 8, dl1 = p1 & 255;
            half8 v0 = t8[(size_t)s0 * 16 + l16];
            half8 v1 = t8[(size_t)s1 * 16 + l16];
            agg_add(acc + dl0 * BPAD, l16, v0);
            agg_add(acc + dl1 * BPAD, l16, v1);
        }
        if (g < nf) {
            unsigned p = (unsigned)__shfl((int)cidx, 4 * g + q);
            int s = p >> 8, dl = p & 255;
            half8 v = t8[(size_t)s * 16 + l16];
            agg_add(acc + dl * BPAD, l16, v);
        }
        int tail = m & 3;
        if (tail) {
            unsigned p = (unsigned)__shfl((int)cidx, 4 * nf + q);
            if (q < tail) {
                int s = p >> 8, dl = p & 255;
                half8 v = t8[(size_t)s * 16 + l16];
                agg_add(acc + dl * BPAD, l16, v);
            }
        }
    }
}

// layer 1: block g owns nodes [g*BN, g*BN+BN); out fp16 = relu(dinv*acc + b)
__global__ __launch_bounds__(256) void k_agg1(const _Float16* __restrict__ tS,
                                              const unsigned* __restrict__ earr,
                                              const int* __restrict__ cellOff,
                                              const float* __restrict__ dinv,
                                              const float* __restrict__ b,
                                              _Float16* __restrict__ out, int n) {
    __shared__ float acc[BN * BPAD];
    const int g = blockIdx.x;
    const int node0 = g * BN;
    // init with self-loop row (tS already scaled by dinv[src])
    for (int s = threadIdx.x; s < BN * 16; s += 256) {
        int ln = s >> 4, c8 = s & 15;
        int node = node0 + ln;
        float* dp = acc + ln * BPAD + c8 * 8;
        if (node < n) {
            half8 v = ((const half8*)tS)[(size_t)node * 16 + c8];
            #pragma unroll
            for (int i = 0; i < 8; ++i) dp[i] = (float)v[i];
        } else {
            #pragma unroll
            for (int i = 0; i < 8; ++i) dp[i] = 0.0f;
        }
    }
    __syncthreads();
    int gs = cellOff[g * SB], ge = cellOff[(g + 1) * SB];
    agg_edges(acc, (const half8*)tS, earr, gs, ge);
    __syncthreads();
    for (int s = threadIdx.x; s < BN * 16; s += 256) {
        int ln = s >> 4, c8 = s & 15;
        int node = node0 + ln;
        if (node >= n) continue;
        float dn = dinv[node];
        const float* ap = acc + ln * BPAD + c8 * 8;
        half8 hv;
        #pragma unroll
        for (int i = 0; i < 8; ++i)
            hv[i] = (_Float16)fmaxf(dn * ap[i] + b[c8 * 8 + i], 0.0f);
        ((half8*)out)[(size_t)node * 16 + c8] = hv;
    }
}

// layer 2 fused with pool head
__global__ __launch_bounds__(256) void k_agg2(const _Float16* __restrict__ tS,
                                              const unsigned* __restrict__ earr,
                                              const int* __restrict__ cellOff,
                                              const float* __restrict__ dinv,
                                              const float* __restrict__ b,
                                              const float* __restrict__ Wp,
                                              const int* __restrict__ batch,
                                              float* __restrict__ pool,
                                              float* __restrict__ cnt, int n) {
    __shared__ float acc[BN * BPAD];
    const int g = blockIdx.x;
    const int node0 = g * BN;
    for (int s = threadIdx.x; s < BN * 16; s += 256) {
        int ln = s >> 4, c8 = s & 15;
        int node = node0 + ln;
        float* dp = acc + ln * BPAD + c8 * 8;
        if (node < n) {
            half8 v = ((const half8*)tS)[(size_t)node * 16 + c8];
            #pragma unroll
            for (int i = 0; i < 8; ++i) dp[i] = (float)v[i];
        } else {
            #pragma unroll
            for (int i = 0; i < 8; ++i) dp[i] = 0.0f;
        }
    }
    __syncthreads();
    int gs = cellOff[g * SB], ge = cellOff[(g + 1) * SB];
    agg_edges(acc, (const half8*)tS, earr, gs, ge);
    __syncthreads();
    int ln = threadIdx.x;
    if (ln < BN) {
        int node = node0 + ln;
        if (node < n) {
            float dn = dinv[node];
            const float* ap = acc + ln * BPAD;
            float s = 0.0f;
            #pragma unroll 8
            for (int f = 0; f < 128; ++f)
                s += fmaxf(dn * ap[f] + b[f], 0.0f) * Wp[f];
            atomicAdd(&pool[batch[node]], s);
            atomicAdd(&cnt[batch[node]], 1.0f);
        }
    }
}

// ---------------------------------------------------------------------------
__global__ __launch_bounds__(256) void final_out_kernel(const float* __restrict__ pool,
                                                        const float* __restrict__ cnt,
                                                        const float* __restrict__ bp,
                                                        float* __restrict__ out, int g) {
    int i = blockIdx.x * 256 + threadIdx.x;
    if (i < g) out[i] = pool[i] / fmaxf(cnt[i], 1.0f) + bp[0];
}

// ---------------------------------------------------------------------------
extern "C" void kernel_launch(void* const* d_in, const int* in_sizes, int n_in,
                              void* d_out, int out_size, void* d_ws, size_t ws_size,
                              hipStream_t stream) {
    const float* x     = (const float*)d_in[0];
    const int*   ei    = (const int*)d_in[1];   // [2, E]: src = ei[0:E], dst = ei[E:2E]
    const int*   batch = (const int*)d_in[2];
    const float* W1    = (const float*)d_in[3];
    const float* b1    = (const float*)d_in[4];
    const float* W2    = (const float*)d_in[5];
    const float* b2    = (const float*)d_in[6];
    const float* Wp    = (const float*)d_in[7];
    const float* bp    = (const float*)d_in[8];
    float* out = (float*)d_out;

    const int E = in_sizes[1] / 2;   // 1,600,000
    const int* src = ei;
    const int* dst = ei + E;

    // workspace layout
    const size_t BUFH = (size_t)NN * H * sizeof(_Float16);   // 25.6 MB
    const size_t NI   = 401408;                               // >= NN*4, 4KB-mult
    const size_t NC   = (size_t)NCELL_PAD * 4;                // 327,680 B
    char* ws = (char*)d_ws;
    size_t off = 0;
    _Float16* tS   = (_Float16*)(ws + off); off += BUFH;     // GEMM outputs (fp16)
    _Float16* h1   = (_Float16*)(ws + off); off += BUFH;     // layer-1 acts (fp16)
    _Float16* xh   = (_Float16*)(ws + off); off += BUFH;     // x cast to fp16
    int*      deg  = (int*)     (ws + off); off += NI;
    float*    dinv = (float*)   (ws + off); off += NI;
    int*   cellCnt = (int*)     (ws + off); off += NC;
    int*   cellOff = (int*)     (ws + off); off += NC;
    int*   cursor  = (int*)     (ws + off); off += NC;
    unsigned* earr = (unsigned*)(ws + off); off += ((size_t)E * 4 + 4095) / 4096 * 4096;
    int*      bsum = (int*)     (ws + off); off += 4096;
    float*    pool = (float*)   (ws + off); off += 2048;
    float*    cnt  = (float*)   (ws + off); off += 2048;

    // --- build grouped edge lists + degree norm ---
    hipMemsetAsync(cellCnt, 0, NC, stream);
    hipMemsetAsync(deg, 0, NN * sizeof(int), stream);
    hipMemsetAsync(pool, 0, 4096, stream);                   // pool + cnt
    k_count<<<(E + 255) / 256, 256, 0, stream>>>(src, dst, cellCnt, deg, E);
    k_scan_block<<<NCELL_PAD / 256, 256, 0, stream>>>(cellCnt, cellOff, bsum, NCELL_PAD);
    k_scan_top<<<1, 512, 0, stream>>>(bsum, NCELL_PAD / 256);
    k_scan_fin2<<<NCELL_PAD / 256, 256, 0, stream>>>(cellOff, bsum, cursor, NCELL_PAD);
    k_dinv<<<(NN + 255) / 256, 256, 0, stream>>>(deg, dinv, NN);
    k_fill2<<<(E + 255) / 256, 256, 0, stream>>>(src, dst, cursor, earr, E);

    // --- x -> fp16 ---
    k_cvt_h<<<(NN * 32 + 255) / 256, 256, 0, stream>>>(x, xh, NN * 32);

    // --- layer 1 ---
    gemm_mfma<<<(NN + 63) / 64, 256, 0, stream>>>(xh, W1, dinv, tS, NN);
    k_agg1<<<NBLK, 256, 0, stream>>>(tS, earr, cellOff, dinv, b1, h1, NN);

    // --- layer 2 ---
    gemm_mfma<<<(NN + 63) / 64, 256, 0, stream>>>(h1, W2, dinv, tS, NN);
    k_agg2<<<NBLK, 256, 0, stream>>>(tS, earr, cellOff, dinv, b2, Wp, batch,
                                     pool, cnt, NN);

    // --- head ---
    final_out_kernel<<<(NG + 255) / 256, 256, 0, stream>>>(pool, cnt, bp, out, NG);
}

// Round 9
// 732.378 us; speedup vs baseline: 4.1688x; 4.1688x over previous
//
#include <hip/hip_runtime.h>
#include <hip/hip_bf16.h>

// Problem constants (match reference)
#define NN 100000
#define NG 512
#define H  128

typedef _Float16 half8 __attribute__((ext_vector_type(8)));
typedef float f32x4 __attribute__((ext_vector_type(4)));

// ---------------------------------------------------------------------------
// CSR build: histogram of dst
__global__ __launch_bounds__(256) void k_hist(const int* __restrict__ dst,
                                              int* __restrict__ deg, int E) {
    int e = blockIdx.x * 256 + threadIdx.x;
    if (e < E) atomicAdd(&deg[dst[e]], 1);
}

// per-block exclusive scan (256 elems), partial sums to bsum
__global__ __launch_bounds__(256) void k_scan_block(const int* __restrict__ deg,
                                                    int* __restrict__ rowptr,
                                                    int* __restrict__ bsum, int n) {
    __shared__ int s[256];
    int tid = threadIdx.x;
    int i = blockIdx.x * 256 + tid;
    int v = (i < n) ? deg[i] : 0;
    s[tid] = v;
    __syncthreads();
    #pragma unroll
    for (int off = 1; off < 256; off <<= 1) {
        int t = (tid >= off) ? s[tid - off] : 0;
        __syncthreads();
        s[tid] += t;
        __syncthreads();
    }
    if (i < n) rowptr[i] = s[tid] - v;            // exclusive within block
    if (tid == 255) bsum[blockIdx.x] = s[255];    // block total
}

// scan of block sums (nb <= 512), single block
__global__ __launch_bounds__(512) void k_scan_top(int* __restrict__ bsum, int nb) {
    __shared__ int s[512];
    int tid = threadIdx.x;
    int v = (tid < nb) ? bsum[tid] : 0;
    s[tid] = v;
    __syncthreads();
    #pragma unroll
    for (int off = 1; off < 512; off <<= 1) {
        int t = (tid >= off) ? s[tid - off] : 0;
        __syncthreads();
        s[tid] += t;
        __syncthreads();
    }
    if (tid < nb) bsum[tid] = s[tid] - v;         // exclusive
}

// finalize: rowptr += block offset; cursor = rowptr; dinv = rsqrt(deg+1)
__global__ __launch_bounds__(256) void k_scan_fin(int* __restrict__ rowptr,
                                                  const int* __restrict__ bsum,
                                                  const int* __restrict__ deg,
                                                  int* __restrict__ cursor,
                                                  float* __restrict__ dinv,
                                                  int n, int E) {
    int i = blockIdx.x * 256 + threadIdx.x;
    if (i >= n) return;
    int r = rowptr[i] + bsum[i >> 8];
    rowptr[i] = r;
    cursor[i] = r;
    dinv[i] = rsqrtf((float)deg[i] + 1.0f);       // +1 self-loop; always > 0
    if (i == 0) rowptr[n] = E;
}

// ---------------------------------------------------------------------------
// transpose + fp16-convert both weights: Wt[n*128+k] = (half)W[k*128+n]
__global__ __launch_bounds__(256) void k_wprep(const float* __restrict__ W1,
                                               const float* __restrict__ W2,
                                               _Float16* __restrict__ Wt1,
                                               _Float16* __restrict__ Wt2) {
    int bb = blockIdx.x;
    const float* W = (bb < 64) ? W1 : W2;
    _Float16* Wt = (bb < 64) ? Wt1 : Wt2;
    int i = (bb & 63) * 256 + threadIdx.x;        // 0..16383
    int k = i >> 7, n = i & 127;
    Wt[n * 128 + k] = (_Float16)W[i];
}

// ---------------------------------------------------------------------------
// Fused: blocks [0,nfb) fill CSR col; blocks [nfb,..) do GEMM1
// (tS = (x@W1)*dinv[row], fp16 out). GEMM uses no LDS: A-frags read fp32 from
// x and converted in-register; B-frags from L2-resident fp16 Wt1.
// MFMA layouts (verified m89/m120): A[m=l16][k=quad*8+j]; B[n=l16][k=quad*8+j];
// C col=l16, row=quad*4+reg.
__global__ __launch_bounds__(256) void k_fill_gemm1(
        const int* __restrict__ src, const int* __restrict__ dst,
        int* __restrict__ cursor, int* __restrict__ col, int E, int nfb,
        const float* __restrict__ x, const _Float16* __restrict__ Wt1,
        const float* __restrict__ dinv, _Float16* __restrict__ tS, int n) {
    if ((int)blockIdx.x < nfb) {
        int e = blockIdx.x * 256 + threadIdx.x;
        if (e >= E) return;
        int d = dst[e];
        int pos = atomicAdd(&cursor[d], 1);
        col[pos] = src[e];
        return;
    }
    const int row0 = ((int)blockIdx.x - nfb) * 64;
    const int tid = threadIdx.x;
    const int w = tid >> 6, lane = tid & 63;
    const int l16 = lane & 15, quad = lane >> 4;
    const int Arow = row0 + w * 16 + l16;
    f32x4 acc[8] = {};
    #pragma unroll
    for (int kk = 0; kk < 4; ++kk) {
        half8 af;
        if (Arow < n) {
            const float* ap = x + (size_t)Arow * H + kk * 32 + quad * 8;
            float4 a0 = ((const float4*)ap)[0];
            float4 a1 = ((const float4*)ap)[1];
            af[0] = (_Float16)a0.x; af[1] = (_Float16)a0.y;
            af[2] = (_Float16)a0.z; af[3] = (_Float16)a0.w;
            af[4] = (_Float16)a1.x; af[5] = (_Float16)a1.y;
            af[6] = (_Float16)a1.z; af[7] = (_Float16)a1.w;
        } else {
            #pragma unroll
            for (int j = 0; j < 8; ++j) af[j] = (_Float16)0.0f;
        }
        #pragma unroll
        for (int nt = 0; nt < 8; ++nt) {
            half8 bf = *((const half8*)(Wt1 + (nt * 16 + l16) * H + kk * 32 + quad * 8));
            acc[nt] = __builtin_amdgcn_mfma_f32_16x16x32_f16(af, bf, acc[nt], 0, 0, 0);
        }
    }
    #pragma unroll
    for (int r = 0; r < 4; ++r) {
        int R = row0 + w * 16 + quad * 4 + r;
        if (R < n) {
            float sc = dinv[R];
            _Float16* crow = tS + (size_t)R * H + l16;
            #pragma unroll
            for (int nt = 0; nt < 8; ++nt)
                crow[nt * 16] = (_Float16)(acc[nt][r] * sc);
        }
    }
}

// ---------------------------------------------------------------------------
// ascending bitonic sort of one value per lane across the 64-lane wave
__device__ __forceinline__ int bitonic64(int v, int lane) {
    #pragma unroll
    for (int k = 2; k <= 64; k <<= 1) {
        #pragma unroll
        for (int j = k >> 1; j > 0; j >>= 1) {
            int p = __shfl_xor(v, j);
            bool up = ((lane & k) == 0);
            bool keepmin = (((lane & j) == 0) == up);
            v = keepmin ? min(v, p) : max(v, p);
        }
    }
    return v;
}

// Gather core, fp16 rows (256B). One wave per node; quarter-wave q handles
// edge slot 4g+q; lane loads 16B of the row. Row indices bulk-loaded,
// in-register sorted ascending (deg<=64 always) for cross-wave phase-coherent
// src sweeps (r5: +9%), broadcast via shfl. fp32 accumulate; after xor-16/32
// all lanes hold the full sum for features l16*8..+7.
__device__ __forceinline__ void gather_rows_h(const half8* __restrict__ t8,
                                              const int* __restrict__ col,
                                              int node, int e0, int end,
                                              float acc[8]) {
    const int lane = threadIdx.x & 63;
    const int q = lane >> 4;
    const int l16 = lane & 15;
    float a0[8] = {}, a1[8] = {};
    if (q == 0) {                                   // self-loop row
        half8 v = t8[(size_t)node * 16 + l16];
        #pragma unroll
        for (int i = 0; i < 8; ++i) a0[i] = (float)v[i];
    }
    const bool small = (end - e0) <= 64;            // wave-uniform
    for (int base = e0; base < end; base += 64) {
        int ce = base + lane;
        int cidx = (ce < end) ? col[ce] : 0x7fffffff;  // pad never consumed
        if (small) cidx = bitonic64(cidx, lane);
        int m = min(64, end - base);
        int nf = m >> 2;                            // full groups of 4 edges
        int g = 0;
        for (; g + 2 <= nf; g += 2) {
            int s0 = __shfl(cidx, 4 * g + q);
            int s1 = __shfl(cidx, 4 * g + 4 + q);
            half8 v0 = t8[(size_t)s0 * 16 + l16];
            half8 v1 = t8[(size_t)s1 * 16 + l16];
            #pragma unroll
            for (int i = 0; i < 8; ++i) {
                a0[i] += (float)v0[i];
                a1[i] += (float)v1[i];
            }
        }
        if (g < nf) {
            int s0 = __shfl(cidx, 4 * g + q);
            half8 v0 = t8[(size_t)s0 * 16 + l16];
            #pragma unroll
            for (int i = 0; i < 8; ++i) a0[i] += (float)v0[i];
        }
        int tail = m & 3;
        if (tail) {
            int s = __shfl(cidx, 4 * nf + q);       // all lanes active here
            if (q < tail) {
                half8 v = t8[(size_t)s * 16 + l16];
                #pragma unroll
                for (int i = 0; i < 8; ++i) a0[i] += (float)v[i];
            }
        }
    }
    #pragma unroll
    for (int i = 0; i < 8; ++i) {
        float t = a0[i] + a1[i];
        t += __shfl_xor(t, 16);
        t += __shfl_xor(t, 32);
        acc[i] = t;
    }
}

// ---------------------------------------------------------------------------
// Fused gather1 + GEMM2: block owns 64 nodes; wave w gathers nodes w*16+i
// (i=0..15) sequentially, writes h1 = relu(dinv*acc+b1) fp16 into LDS tile;
// then per-wave MFMA with global fp16 Wt2 emits tS2 = (h1@W2)*dinv[row].
#define LDA 136   // 128 + 8 fp16 pad
__global__ __launch_bounds__(256) void k_gather1f(const _Float16* __restrict__ tS,
                                                  const int* __restrict__ rowptr,
                                                  const int* __restrict__ col,
                                                  const float* __restrict__ dinv,
                                                  const float* __restrict__ b,
                                                  const _Float16* __restrict__ Wt2,
                                                  _Float16* __restrict__ tS2, int n) {
    __shared__ _Float16 As[64 * LDA];
    const int tid = threadIdx.x;
    const int w = tid >> 6, lane = tid & 63;
    const int q = lane >> 4, l16 = lane & 15, quad = lane >> 4;
    const int node0 = blockIdx.x * 64;
    const float4* b4 = (const float4*)b;
    float4 bb0 = b4[2 * l16], bb1 = b4[2 * l16 + 1];

    for (int i = 0; i < 16; ++i) {
        int node = node0 + w * 16 + i;
        half8 hv;
        #pragma unroll
        for (int j = 0; j < 8; ++j) hv[j] = (_Float16)0.0f;
        if (node < n) {
            int e0 = rowptr[node], end = rowptr[node + 1];
            float acc[8];
            gather_rows_h((const half8*)tS, col, node, e0, end, acc);
            float dn = dinv[node];
            hv[0] = (_Float16)fmaxf(dn * acc[0] + bb0.x, 0.0f);
            hv[1] = (_Float16)fmaxf(dn * acc[1] + bb0.y, 0.0f);
            hv[2] = (_Float16)fmaxf(dn * acc[2] + bb0.z, 0.0f);
            hv[3] = (_Float16)fmaxf(dn * acc[3] + bb0.w, 0.0f);
            hv[4] = (_Float16)fmaxf(dn * acc[4] + bb1.x, 0.0f);
            hv[5] = (_Float16)fmaxf(dn * acc[5] + bb1.y, 0.0f);
            hv[6] = (_Float16)fmaxf(dn * acc[6] + bb1.z, 0.0f);
            hv[7] = (_Float16)fmaxf(dn * acc[7] + bb1.w, 0.0f);
        }
        if (q == 0)
            *((half8*)(As + (w * 16 + i) * LDA + l16 * 8)) = hv;
    }
    __syncthreads();

    // GEMM2 on the LDS tile
    f32x4 acc2[8] = {};
    const _Float16* aBase = As + (w * 16 + l16) * LDA + quad * 8;
    #pragma unroll
    for (int kk = 0; kk < 4; ++kk) {
        half8 af = *((const half8*)(aBase + kk * 32));
        #pragma unroll
        for (int nt = 0; nt < 8; ++nt) {
            half8 bf = *((const half8*)(Wt2 + (nt * 16 + l16) * H + kk * 32 + quad * 8));
            acc2[nt] = __builtin_amdgcn_mfma_f32_16x16x32_f16(af, bf, acc2[nt], 0, 0, 0);
        }
    }
    #pragma unroll
    for (int r = 0; r < 4; ++r) {
        int R = node0 + w * 16 + quad * 4 + r;
        if (R < n) {
            float sc = dinv[R];
            _Float16* crow = tS2 + (size_t)R * H + l16;
            #pragma unroll
            for (int nt = 0; nt < 8; ++nt)
                crow[nt * 16] = (_Float16)(acc2[nt][r] * sc);
        }
    }
}

// ---------------------------------------------------------------------------
// gather layer 2 fused with pool head: v = relu(...); pool[batch[n]] += dot(v, Wp)
__global__ __launch_bounds__(256) void k_gather2(const _Float16* __restrict__ tS,
                                                 const int* __restrict__ rowptr,
                                                 const int* __restrict__ col,
                                                 const float* __restrict__ dinv,
                                                 const float* __restrict__ b,
                                                 const float* __restrict__ Wp,
                                                 const int* __restrict__ batch,
                                                 float* __restrict__ pool,
                                                 float* __restrict__ cnt, int n) {
    int node = blockIdx.x * 4 + (threadIdx.x >> 6);
    int lane = threadIdx.x & 63;
    int l16 = lane & 15;
    if (node >= n) return;
    int e0 = rowptr[node], end = rowptr[node + 1];
    float acc[8];
    gather_rows_h((const half8*)tS, col, node, e0, end, acc);
    float dn = dinv[node];
    const float4* b4 = (const float4*)b;
    const float4* w4 = (const float4*)Wp;
    float4 bb0 = b4[2 * l16], bb1 = b4[2 * l16 + 1];
    float4 wp0 = w4[2 * l16], wp1 = w4[2 * l16 + 1];
    float s = fmaxf(dn * acc[0] + bb0.x, 0.0f) * wp0.x +
              fmaxf(dn * acc[1] + bb0.y, 0.0f) * wp0.y +
              fmaxf(dn * acc[2] + bb0.z, 0.0f) * wp0.z +
              fmaxf(dn * acc[3] + bb0.w, 0.0f) * wp0.w +
              fmaxf(dn * acc[4] + bb1.x, 0.0f) * wp1.x +
              fmaxf(dn * acc[5] + bb1.y, 0.0f) * wp1.y +
              fmaxf(dn * acc[6] + bb1.z, 0.0f) * wp1.z +
              fmaxf(dn * acc[7] + bb1.w, 0.0f) * wp1.w;
    s += __shfl_xor(s, 1);
    s += __shfl_xor(s, 2);
    s += __shfl_xor(s, 4);
    s += __shfl_xor(s, 8);
    if (lane == 0) {
        int g = batch[node];
        atomicAdd(&pool[g], s);
        atomicAdd(&cnt[g], 1.0f);
    }
}

// ---------------------------------------------------------------------------
__global__ __launch_bounds__(256) void final_out_kernel(const float* __restrict__ pool,
                                                        const float* __restrict__ cnt,
                                                        const float* __restrict__ bp,
                                                        float* __restrict__ out, int g) {
    int i = blockIdx.x * 256 + threadIdx.x;
    if (i < g) out[i] = pool[i] / fmaxf(cnt[i], 1.0f) + bp[0];
}

// ---------------------------------------------------------------------------
extern "C" void kernel_launch(void* const* d_in, const int* in_sizes, int n_in,
                              void* d_out, int out_size, void* d_ws, size_t ws_size,
                              hipStream_t stream) {
    const float* x     = (const float*)d_in[0];
    const int*   ei    = (const int*)d_in[1];   // [2, E]: src = ei[0:E], dst = ei[E:2E]
    const int*   batch = (const int*)d_in[2];
    const float* W1    = (const float*)d_in[3];
    const float* b1    = (const float*)d_in[4];
    const float* W2    = (const float*)d_in[5];
    const float* b2    = (const float*)d_in[6];
    const float* Wp    = (const float*)d_in[7];
    const float* bp    = (const float*)d_in[8];
    float* out = (float*)d_out;

    const int E = in_sizes[1] / 2;   // 1,600,000
    const int* src = ei;
    const int* dst = ei + E;

    // workspace layout
    const size_t BUFH = (size_t)NN * H * sizeof(_Float16);   // 25.6 MB
    const size_t NI   = 401408;                               // >= (NN+1)*4, 4KB-mult
    char* ws = (char*)d_ws;
    size_t off = 0;
    _Float16* tS   = (_Float16*)(ws + off); off += BUFH;     // GEMM1 out (fp16)
    _Float16* tS2  = (_Float16*)(ws + off); off += BUFH;     // fused L1+GEMM2 out
    int*      deg  = (int*)     (ws + off); off += NI;
    int*   rowptr  = (int*)     (ws + off); off += NI;
    int*   cursor  = (int*)     (ws + off); off += NI;
    float*    dinv = (float*)   (ws + off); off += NI;
    int*      col  = (int*)     (ws + off); off += ((size_t)E * 4 + 4095) / 4096 * 4096;
    _Float16* Wt1  = (_Float16*)(ws + off); off += 32768;
    _Float16* Wt2  = (_Float16*)(ws + off); off += 32768;
    int*      bsum = (int*)     (ws + off); off += 4096;
    float*    pool = (float*)   (ws + off); off += 2048;
    float*    cnt  = (float*)   (ws + off); off += 2048;

    const int NB  = (NN + 255) / 256;   // 391 scan blocks
    const int NFB = (E + 255) / 256;    // 6250 fill blocks
    const int NGB = (NN + 63) / 64;     // 1563 gemm/gather1 blocks

    // --- weights prep + CSR build + degree norm ---
    hipMemsetAsync(deg, 0, NN * sizeof(int), stream);
    hipMemsetAsync(pool, 0, 4096, stream);                   // pool + cnt
    k_wprep<<<128, 256, 0, stream>>>(W1, W2, Wt1, Wt2);
    k_hist<<<NFB, 256, 0, stream>>>(dst, deg, E);
    k_scan_block<<<NB, 256, 0, stream>>>(deg, rowptr, bsum, NN);
    k_scan_top<<<1, 512, 0, stream>>>(bsum, NB);
    k_scan_fin<<<NB, 256, 0, stream>>>(rowptr, bsum, deg, cursor, dinv, NN, E);

    // --- fill CSR  ∥  GEMM1 (one dispatch, disjoint block ranges) ---
    k_fill_gemm1<<<NFB + NGB, 256, 0, stream>>>(src, dst, cursor, col, E, NFB,
                                                x, Wt1, dinv, tS, NN);

    // --- layer 1 gather + GEMM2 (fused) ---
    k_gather1f<<<NGB, 256, 0, stream>>>(tS, rowptr, col, dinv, b1, Wt2, tS2, NN);

    // --- layer 2 gather + pool head ---
    k_gather2<<<(NN + 3) / 4, 256, 0, stream>>>(tS2, rowptr, col, dinv, b2, Wp,
                                                batch, pool, cnt, NN);

    // --- head ---
    final_out_kernel<<<(NG + 255) / 256, 256, 0, stream>>>(pool, cnt, bp, out, NG);
}

// Round 10
// 688.023 us; speedup vs baseline: 4.4376x; 1.0645x over previous
//
#include <hip/hip_runtime.h>
#include <hip/hip_bf16.h>

// Problem constants (match reference)
#define NN 100000
#define NG 512
#define H  128

typedef _Float16 half8 __attribute__((ext_vector_type(8)));
typedef float f32x4 __attribute__((ext_vector_type(4)));

// ---------------------------------------------------------------------------
// CSR build: histogram of dst
__global__ __launch_bounds__(256) void k_hist(const int* __restrict__ dst,
                                              int* __restrict__ deg, int E) {
    int e = blockIdx.x * 256 + threadIdx.x;
    if (e < E) atomicAdd(&deg[dst[e]], 1);
}

// per-block exclusive scan (256 elems), partial sums to bsum
__global__ __launch_bounds__(256) void k_scan_block(const int* __restrict__ deg,
                                                    int* __restrict__ rowptr,
                                                    int* __restrict__ bsum, int n) {
    __shared__ int s[256];
    int tid = threadIdx.x;
    int i = blockIdx.x * 256 + tid;
    int v = (i < n) ? deg[i] : 0;
    s[tid] = v;
    __syncthreads();
    #pragma unroll
    for (int off = 1; off < 256; off <<= 1) {
        int t = (tid >= off) ? s[tid - off] : 0;
        __syncthreads();
        s[tid] += t;
        __syncthreads();
    }
    if (i < n) rowptr[i] = s[tid] - v;            // exclusive within block
    if (tid == 255) bsum[blockIdx.x] = s[255];    // block total
}

// scan of block sums (nb <= 512), single block
__global__ __launch_bounds__(512) void k_scan_top(int* __restrict__ bsum, int nb) {
    __shared__ int s[512];
    int tid = threadIdx.x;
    int v = (tid < nb) ? bsum[tid] : 0;
    s[tid] = v;
    __syncthreads();
    #pragma unroll
    for (int off = 1; off < 512; off <<= 1) {
        int t = (tid >= off) ? s[tid - off] : 0;
        __syncthreads();
        s[tid] += t;
        __syncthreads();
    }
    if (tid < nb) bsum[tid] = s[tid] - v;         // exclusive
}

// finalize: rowptr += block offset; cursor = rowptr; dinv = rsqrt(deg+1)
__global__ __launch_bounds__(256) void k_scan_fin(int* __restrict__ rowptr,
                                                  const int* __restrict__ bsum,
                                                  const int* __restrict__ deg,
                                                  int* __restrict__ cursor,
                                                  float* __restrict__ dinv,
                                                  int n, int E) {
    int i = blockIdx.x * 256 + threadIdx.x;
    if (i >= n) return;
    int r = rowptr[i] + bsum[i >> 8];
    rowptr[i] = r;
    cursor[i] = r;
    dinv[i] = rsqrtf((float)deg[i] + 1.0f);       // +1 self-loop; always > 0
    if (i == 0) rowptr[n] = E;
}

// ---------------------------------------------------------------------------
// transpose + fp16-convert both weights: Wt[n*128+k] = (half)W[k*128+n]
__global__ __launch_bounds__(256) void k_wprep(const float* __restrict__ W1,
                                               const float* __restrict__ W2,
                                               _Float16* __restrict__ Wt1,
                                               _Float16* __restrict__ Wt2) {
    int bb = blockIdx.x;
    const float* W = (bb < 64) ? W1 : W2;
    _Float16* Wt = (bb < 64) ? Wt1 : Wt2;
    int i = (bb & 63) * 256 + threadIdx.x;        // 0..16383
    int k = i >> 7, n = i & 127;
    Wt[n * 128 + k] = (_Float16)W[i];
}

// ---------------------------------------------------------------------------
// Fused: blocks [0,nfb) fill CSR col; blocks [nfb,..) do GEMM1
// (tS = (x@W1)*dinv[row], fp16 out). GEMM uses no LDS: A-frags read fp32 from
// x and converted in-register; B-frags from L2-resident fp16 Wt1.
// MFMA layouts (verified m89/m120): A[m=l16][k=quad*8+j]; B[n=l16][k=quad*8+j];
// C col=l16, row=quad*4+reg.
__global__ __launch_bounds__(256) void k_fill_gemm1(
        const int* __restrict__ src, const int* __restrict__ dst,
        int* __restrict__ cursor, int* __restrict__ col, int E, int nfb,
        const float* __restrict__ x, const _Float16* __restrict__ Wt1,
        const float* __restrict__ dinv, _Float16* __restrict__ tS, int n) {
    if ((int)blockIdx.x < nfb) {
        int e = blockIdx.x * 256 + threadIdx.x;
        if (e >= E) return;
        int d = dst[e];
        int pos = atomicAdd(&cursor[d], 1);
        col[pos] = src[e];
        return;
    }
    const int row0 = ((int)blockIdx.x - nfb) * 64;
    const int tid = threadIdx.x;
    const int w = tid >> 6, lane = tid & 63;
    const int l16 = lane & 15, quad = lane >> 4;
    const int Arow = row0 + w * 16 + l16;
    f32x4 acc[8] = {};
    #pragma unroll
    for (int kk = 0; kk < 4; ++kk) {
        half8 af;
        if (Arow < n) {
            const float* ap = x + (size_t)Arow * H + kk * 32 + quad * 8;
            float4 a0 = ((const float4*)ap)[0];
            float4 a1 = ((const float4*)ap)[1];
            af[0] = (_Float16)a0.x; af[1] = (_Float16)a0.y;
            af[2] = (_Float16)a0.z; af[3] = (_Float16)a0.w;
            af[4] = (_Float16)a1.x; af[5] = (_Float16)a1.y;
            af[6] = (_Float16)a1.z; af[7] = (_Float16)a1.w;
        } else {
            #pragma unroll
            for (int j = 0; j < 8; ++j) af[j] = (_Float16)0.0f;
        }
        #pragma unroll
        for (int nt = 0; nt < 8; ++nt) {
            half8 bf = *((const half8*)(Wt1 + (nt * 16 + l16) * H + kk * 32 + quad * 8));
            acc[nt] = __builtin_amdgcn_mfma_f32_16x16x32_f16(af, bf, acc[nt], 0, 0, 0);
        }
    }
    #pragma unroll
    for (int r = 0; r < 4; ++r) {
        int R = row0 + w * 16 + quad * 4 + r;
        if (R < n) {
            float sc = dinv[R];
            _Float16* crow = tS + (size_t)R * H + l16;
            #pragma unroll
            for (int nt = 0; nt < 8; ++nt)
                crow[nt * 16] = (_Float16)(acc[nt][r] * sc);
        }
    }
}

// ---------------------------------------------------------------------------
// GEMM2, LDS-free: tS2 = (h1 @ W2) * dinv[row]; A-frags straight from global
// fp16 h1, B-frags from L2-resident Wt2. 64 rows/block, 4 waves.
__global__ __launch_bounds__(256) void k_gemm2(const _Float16* __restrict__ h1,
                                               const _Float16* __restrict__ Wt2,
                                               const float* __restrict__ dinv,
                                               _Float16* __restrict__ tS2, int n) {
    const int row0 = blockIdx.x * 64;
    const int tid = threadIdx.x;
    const int w = tid >> 6, lane = tid & 63;
    const int l16 = lane & 15, quad = lane >> 4;
    const int Arow = row0 + w * 16 + l16;
    f32x4 acc[8] = {};
    #pragma unroll
    for (int kk = 0; kk < 4; ++kk) {
        half8 af;
        if (Arow < n) {
            af = ((const half8*)(h1 + (size_t)Arow * H))[kk * 4 + quad];
        } else {
            #pragma unroll
            for (int j = 0; j < 8; ++j) af[j] = (_Float16)0.0f;
        }
        #pragma unroll
        for (int nt = 0; nt < 8; ++nt) {
            half8 bf = *((const half8*)(Wt2 + (nt * 16 + l16) * H + kk * 32 + quad * 8));
            acc[nt] = __builtin_amdgcn_mfma_f32_16x16x32_f16(af, bf, acc[nt], 0, 0, 0);
        }
    }
    #pragma unroll
    for (int r = 0; r < 4; ++r) {
        int R = row0 + w * 16 + quad * 4 + r;
        if (R < n) {
            float sc = dinv[R];
            _Float16* crow = tS2 + (size_t)R * H + l16;
            #pragma unroll
            for (int nt = 0; nt < 8; ++nt)
                crow[nt * 16] = (_Float16)(acc[nt][r] * sc);
        }
    }
}

// ---------------------------------------------------------------------------
// Gather core, fp16 rows (256B). One wave per node; quarter-wave q handles
// edge slot 4g+q; lane loads 16B (8 halves) of the row => one 64-lane load
// fetches FOUR rows. col indices bulk-loaded 64 at a time, broadcast by shfl.
// fp32 accumulate; after xor-16/32 all lanes hold the sum for feats l16*8..+7.
__device__ __forceinline__ void gather_rows_h(const half8* __restrict__ t8,
                                              const int* __restrict__ col,
                                              int node, int e0, int end,
                                              float acc[8]) {
    const int lane = threadIdx.x & 63;
    const int q = lane >> 4;
    const int l16 = lane & 15;
    float a0[8] = {}, a1[8] = {};
    if (q == 0) {                                   // self-loop row
        half8 v = t8[(size_t)node * 16 + l16];
        #pragma unroll
        for (int i = 0; i < 8; ++i) a0[i] = (float)v[i];
    }
    for (int base = e0; base < end; base += 64) {
        int ce = base + lane;
        int cidx = (ce < end) ? col[ce] : 0;
        int m = min(64, end - base);
        int nf = m >> 2;                            // full groups of 4 edges
        int g = 0;
        for (; g + 2 <= nf; g += 2) {
            int s0 = __shfl(cidx, 4 * g + q);
            int s1 = __shfl(cidx, 4 * g + 4 + q);
            half8 v0 = t8[(size_t)s0 * 16 + l16];
            half8 v1 = t8[(size_t)s1 * 16 + l16];
            #pragma unroll
            for (int i = 0; i < 8; ++i) {
                a0[i] += (float)v0[i];
                a1[i] += (float)v1[i];
            }
        }
        if (g < nf) {
            int s0 = __shfl(cidx, 4 * g + q);
            half8 v0 = t8[(size_t)s0 * 16 + l16];
            #pragma unroll
            for (int i = 0; i < 8; ++i) a0[i] += (float)v0[i];
        }
        int tail = m & 3;
        if (tail) {
            int s = __shfl(cidx, 4 * nf + q);       // all lanes active here
            if (q < tail) {
                half8 v = t8[(size_t)s * 16 + l16];
                #pragma unroll
                for (int i = 0; i < 8; ++i) a0[i] += (float)v[i];
            }
        }
    }
    #pragma unroll
    for (int i = 0; i < 8; ++i) {
        float t = a0[i] + a1[i];
        t += __shfl_xor(t, 16);
        t += __shfl_xor(t, 32);
        acc[i] = t;
    }
}

// gather layer 1: out (fp16) = relu(dinv[n]*(tS[n] + sum in-edges) + b)
__global__ __launch_bounds__(256) void k_gather1(const _Float16* __restrict__ tS,
                                                 const int* __restrict__ rowptr,
                                                 const int* __restrict__ col,
                                                 const float* __restrict__ dinv,
                                                 const float* __restrict__ b,
                                                 _Float16* __restrict__ out, int n) {
    int node = blockIdx.x * 4 + (threadIdx.x >> 6);
    int lane = threadIdx.x & 63;
    int q = lane >> 4, l16 = lane & 15;
    if (node >= n) return;
    int e0 = rowptr[node], end = rowptr[node + 1];
    float acc[8];
    gather_rows_h((const half8*)tS, col, node, e0, end, acc);
    if (q == 0) {
        float dn = dinv[node];
        const float4* b4 = (const float4*)b;
        float4 bb0 = b4[2 * l16], bb1 = b4[2 * l16 + 1];
        half8 hv;
        hv[0] = (_Float16)fmaxf(dn * acc[0] + bb0.x, 0.0f);
        hv[1] = (_Float16)fmaxf(dn * acc[1] + bb0.y, 0.0f);
        hv[2] = (_Float16)fmaxf(dn * acc[2] + bb0.z, 0.0f);
        hv[3] = (_Float16)fmaxf(dn * acc[3] + bb0.w, 0.0f);
        hv[4] = (_Float16)fmaxf(dn * acc[4] + bb1.x, 0.0f);
        hv[5] = (_Float16)fmaxf(dn * acc[5] + bb1.y, 0.0f);
        hv[6] = (_Float16)fmaxf(dn * acc[6] + bb1.z, 0.0f);
        hv[7] = (_Float16)fmaxf(dn * acc[7] + bb1.w, 0.0f);
        ((half8*)out)[(size_t)node * 16 + l16] = hv;
    }
}

// gather layer 2 fused with pool head: v = relu(...); pool[batch[n]] += dot(v, Wp)
__global__ __launch_bounds__(256) void k_gather2(const _Float16* __restrict__ tS,
                                                 const int* __restrict__ rowptr,
                                                 const int* __restrict__ col,
                                                 const float* __restrict__ dinv,
                                                 const float* __restrict__ b,
                                                 const float* __restrict__ Wp,
                                                 const int* __restrict__ batch,
                                                 float* __restrict__ pool,
                                                 float* __restrict__ cnt, int n) {
    int node = blockIdx.x * 4 + (threadIdx.x >> 6);
    int lane = threadIdx.x & 63;
    int l16 = lane & 15;
    if (node >= n) return;
    int e0 = rowptr[node], end = rowptr[node + 1];
    float acc[8];
    gather_rows_h((const half8*)tS, col, node, e0, end, acc);
    float dn = dinv[node];
    const float4* b4 = (const float4*)b;
    const float4* w4 = (const float4*)Wp;
    float4 bb0 = b4[2 * l16], bb1 = b4[2 * l16 + 1];
    float4 wp0 = w4[2 * l16], wp1 = w4[2 * l16 + 1];
    float s = fmaxf(dn * acc[0] + bb0.x, 0.0f) * wp0.x +
              fmaxf(dn * acc[1] + bb0.y, 0.0f) * wp0.y +
              fmaxf(dn * acc[2] + bb0.z, 0.0f) * wp0.z +
              fmaxf(dn * acc[3] + bb0.w, 0.0f) * wp0.w +
              fmaxf(dn * acc[4] + bb1.x, 0.0f) * wp1.x +
              fmaxf(dn * acc[5] + bb1.y, 0.0f) * wp1.y +
              fmaxf(dn * acc[6] + bb1.z, 0.0f) * wp1.z +
              fmaxf(dn * acc[7] + bb1.w, 0.0f) * wp1.w;
    s += __shfl_xor(s, 1);
    s += __shfl_xor(s, 2);
    s += __shfl_xor(s, 4);
    s += __shfl_xor(s, 8);
    if (lane == 0) {
        int g = batch[node];
        atomicAdd(&pool[g], s);
        atomicAdd(&cnt[g], 1.0f);
    }
}

// ---------------------------------------------------------------------------
__global__ __launch_bounds__(256) void final_out_kernel(const float* __restrict__ pool,
                                                        const float* __restrict__ cnt,
                                                        const float* __restrict__ bp,
                                                        float* __restrict__ out, int g) {
    int i = blockIdx.x * 256 + threadIdx.x;
    if (i < g) out[i] = pool[i] / fmaxf(cnt[i], 1.0f) + bp[0];
}

// ---------------------------------------------------------------------------
extern "C" void kernel_launch(void* const* d_in, const int* in_sizes, int n_in,
                              void* d_out, int out_size, void* d_ws, size_t ws_size,
                              hipStream_t stream) {
    const float* x     = (const float*)d_in[0];
    const int*   ei    = (const int*)d_in[1];   // [2, E]: src = ei[0:E], dst = ei[E:2E]
    const int*   batch = (const int*)d_in[2];
    const float* W1    = (const float*)d_in[3];
    const float* b1    = (const float*)d_in[4];
    const float* W2    = (const float*)d_in[5];
    const float* b2    = (const float*)d_in[6];
    const float* Wp    = (const float*)d_in[7];
    const float* bp    = (const float*)d_in[8];
    float* out = (float*)d_out;

    const int E = in_sizes[1] / 2;   // 1,600,000
    const int* src = ei;
    const int* dst = ei + E;

    // workspace layout
    const size_t BUFH = (size_t)NN * H * sizeof(_Float16);   // 25.6 MB
    const size_t NI   = 401408;                               // >= (NN+1)*4, 4KB-mult
    char* ws = (char*)d_ws;
    size_t off = 0;
    _Float16* tS   = (_Float16*)(ws + off); off += BUFH;     // GEMM1 out (fp16)
    _Float16* h1   = (_Float16*)(ws + off); off += BUFH;     // layer-1 acts (fp16)
    _Float16* tS2  = (_Float16*)(ws + off); off += BUFH;     // GEMM2 out (fp16)
    int*      deg  = (int*)     (ws + off); off += NI;
    int*   rowptr  = (int*)     (ws + off); off += NI;
    int*   cursor  = (int*)     (ws + off); off += NI;
    float*    dinv = (float*)   (ws + off); off += NI;
    int*      col  = (int*)     (ws + off); off += ((size_t)E * 4 + 4095) / 4096 * 4096;
    _Float16* Wt1  = (_Float16*)(ws + off); off += 32768;
    _Float16* Wt2  = (_Float16*)(ws + off); off += 32768;
    int*      bsum = (int*)     (ws + off); off += 4096;
    float*    pool = (float*)   (ws + off); off += 2048;
    float*    cnt  = (float*)   (ws + off); off += 2048;

    const int NB  = (NN + 255) / 256;   // 391 scan blocks
    const int NFB = (E + 255) / 256;    // 6250 fill blocks
    const int NGB = (NN + 63) / 64;     // 1563 gemm blocks

    // --- weights prep + CSR build + degree norm ---
    hipMemsetAsync(deg, 0, NN * sizeof(int), stream);
    hipMemsetAsync(pool, 0, 4096, stream);                   // pool + cnt
    k_wprep<<<128, 256, 0, stream>>>(W1, W2, Wt1, Wt2);
    k_hist<<<NFB, 256, 0, stream>>>(dst, deg, E);
    k_scan_block<<<NB, 256, 0, stream>>>(deg, rowptr, bsum, NN);
    k_scan_top<<<1, 512, 0, stream>>>(bsum, NB);
    k_scan_fin<<<NB, 256, 0, stream>>>(rowptr, bsum, deg, cursor, dinv, NN, E);

    // --- fill CSR  ∥  GEMM1 (one dispatch, disjoint block ranges) ---
    k_fill_gemm1<<<NFB + NGB, 256, 0, stream>>>(src, dst, cursor, col, E, NFB,
                                                x, Wt1, dinv, tS, NN);

    // --- layer 1: gather (wave/node) then LDS-free MFMA GEMM2 ---
    k_gather1<<<(NN + 3) / 4, 256, 0, stream>>>(tS, rowptr, col, dinv, b1, h1, NN);
    k_gemm2<<<NGB, 256, 0, stream>>>(h1, Wt2, dinv, tS2, NN);

    // --- layer 2 gather + pool head ---
    k_gather2<<<(NN + 3) / 4, 256, 0, stream>>>(tS2, rowptr, col, dinv, b2, Wp,
                                                batch, pool, cnt, NN);

    // --- head ---
    final_out_kernel<<<(NG + 255) / 256, 256, 0, stream>>>(pool, cnt, bp, out, NG);
}